// Round 16
// baseline (504.804 us; speedup 1.0000x reference)
//
#include <hip/hip_runtime.h>
#include <hip/hip_bf16.h>

#define B_ 4
#define S_ 2048
#define HID_ 2048
#define NH_ 8
#define HD_ 256
#define QKVN 2560

typedef unsigned short u16;
typedef unsigned long long ull;
typedef __attribute__((ext_vector_type(4))) float f32x4;
typedef __attribute__((ext_vector_type(16))) float f32x16;
typedef __attribute__((ext_vector_type(8))) short bf16x8;

__device__ __forceinline__ float bf2f(u16 u) {
  union { unsigned int i; float f; } v; v.i = ((unsigned int)u) << 16; return v.f;
}
__device__ __forceinline__ u16 f2bf(float f) {
  union { unsigned int i; float f; } v; v.f = f;
  unsigned int r = v.i + 0x7fffu + ((v.i >> 16) & 1u);
  return (u16)(r >> 16);
}

// ---------------- cast x (f32 -> bf16), 8 elems/thread ----------------
__global__ void cast_f32_bf16(const float* __restrict__ in, u16* __restrict__ out, int n8) {
  int i = blockIdx.x * blockDim.x + threadIdx.x;
  int stride = gridDim.x * blockDim.x;
  for (; i < n8; i += stride) {
    const float4* p = (const float4*)(in + (size_t)i * 8);
    float4 a = p[0], b = p[1];
    u16 o[8] = {f2bf(a.x), f2bf(a.y), f2bf(a.z), f2bf(a.w),
                f2bf(b.x), f2bf(b.y), f2bf(b.z), f2bf(b.w)};
    *(uint4*)(out + (size_t)i * 8) = *(const uint4*)o;
  }
}

// ------------- transpose + cast: in[R][C] f32 -> out[C][R] bf16 -------------
__global__ void transpose_cast(const float* __restrict__ in, u16* __restrict__ out, int R, int C) {
  __shared__ float t[32][33];
  int c0 = blockIdx.x * 32, r0 = blockIdx.y * 32;
  int tx = threadIdx.x, ty = threadIdx.y;
#pragma unroll
  for (int i = 0; i < 4; ++i)
    t[ty + i * 8][tx] = in[(size_t)(r0 + ty + i * 8) * C + c0 + tx];
  __syncthreads();
#pragma unroll
  for (int i = 0; i < 4; ++i)
    out[(size_t)(c0 + ty + i * 8) * R + r0 + tx] = f2bf(t[tx][ty + i * 8]);
}

// ------------- transpose bf16 (per-batch): in[R][C] -> out[C][R] -------------
__global__ void transpose_bf16(const u16* __restrict__ in, u16* __restrict__ out, int R, int C) {
  __shared__ u16 t[32][33];
  in += (size_t)blockIdx.z * R * C;
  out += (size_t)blockIdx.z * R * C;
  int c0 = blockIdx.x * 32, r0 = blockIdx.y * 32;
  int tx = threadIdx.x, ty = threadIdx.y;
#pragma unroll
  for (int i = 0; i < 4; ++i)
    t[ty + i * 8][tx] = in[(size_t)(r0 + ty + i * 8) * C + c0 + tx];
  __syncthreads();
#pragma unroll
  for (int i = 0; i < 4; ++i)
    out[(size_t)(c0 + ty + i * 8) * R + r0 + tx] = t[tx][ty + i * 8];
}

// ================= 256x256 8-phase GEMM (R10-proven) =================
#define BAR() __builtin_amdgcn_s_barrier()
#define PRIO1() __builtin_amdgcn_s_setprio(1)
#define PRIO0() __builtin_amdgcn_s_setprio(0)
#define SB0() __builtin_amdgcn_sched_barrier(0)
#define WVM(n)                                                                                    \
  do {                                                                                            \
    SB0();                                                                                        \
    asm volatile("s_waitcnt vmcnt(" #n ")" ::: "memory");                                         \
    SB0();                                                                                        \
  } while (0)

#define STG(mat, b0, h, T, ldsb)                                                                  \
  do {                                                                                            \
    _Pragma("unroll") for (int q = 0; q < 2; ++q) {                                               \
      int idx = q * 512 + tid;                                                                    \
      int rl = idx >> 3, gp = idx & 7;                                                            \
      const u16* s = (mat) + (size_t)((b0) + (h) * 128 + rl) * K + (T) * 64 +                     \
                     ((gp ^ (rl & 7)) << 3);                                                      \
      __builtin_amdgcn_global_load_lds((const __attribute__((address_space(1))) void*)s,          \
          (__attribute__((address_space(3))) void*)((ldsb) + (h) * 8192 + idx * 8), 16, 0, 0);    \
    }                                                                                             \
  } while (0)

#define LOAD_A(buf, mib)                                                                          \
  _Pragma("unroll") for (int mi = 0; mi < 4; ++mi)                                                \
  _Pragma("unroll") for (int ks = 0; ks < 2; ++ks)                                                \
    af[mi][ks] = *(const bf16x8*)((buf) + (wr * 128 + ((mib) + mi) * 16 + l15) * 64 +             \
                                  (((ks * 4 + lg) ^ (l15 & 7)) << 3));

#define LOAD_B(buf, nib)                                                                          \
  _Pragma("unroll") for (int ni = 0; ni < 2; ++ni)                                                \
  _Pragma("unroll") for (int ks = 0; ks < 2; ++ks)                                                \
    bfr[(nib) + ni][ks] = *(const bf16x8*)((buf) + (wc * 64 + ((nib) + ni) * 16 + l15) * 64 +     \
                                           (((ks * 4 + lg) ^ (l15 & 7)) << 3));

#define MFMA16(accb, nib)                                                                         \
  _Pragma("unroll") for (int mi = 0; mi < 4; ++mi)                                                \
  _Pragma("unroll") for (int ni = 0; ni < 2; ++ni)                                                \
  _Pragma("unroll") for (int ks = 0; ks < 2; ++ks)                                                \
    acc[(accb) + mi][(nib) + ni] = __builtin_amdgcn_mfma_f32_16x16x32_bf16(                       \
        af[mi][ks], bfr[(nib) + ni][ks], acc[(accb) + mi][(nib) + ni], 0, 0, 0);

template <bool OUT_F32>
__global__ __launch_bounds__(512, 2) void gemm256(const u16* __restrict__ A, const u16* __restrict__ BT,
                                                  const float* __restrict__ bias, void* __restrict__ Cout,
                                                  int M, int N, int K) {
  __shared__ u16 Asm[2][16384];
  __shared__ u16 Bsm[2][16384];
  int nwg = gridDim.x;
  int bid = (int)blockIdx.x;
  bid = (bid & 7) * (nwg >> 3) + (bid >> 3);  // XCD swizzle (nwg % 8 == 0)
  int ntn = N >> 8;
  int m0 = (bid / ntn) << 8, n0 = (bid % ntn) << 8;
  int tid = threadIdx.x, w = tid >> 6, lane = tid & 63;
  int wr = w >> 2, wc = w & 3;
  int l15 = lane & 15, lg = lane >> 4;
  int NT = K >> 6;
  u16* A0b = &Asm[0][0]; u16* A1b = &Asm[1][0];
  u16* B0b = &Bsm[0][0]; u16* B1b = &Bsm[1][0];
  f32x4 acc[8][4] = {};
  bf16x8 af[4][2], bfr[4][2];

  STG(A, m0, 0, 0, A0b); STG(A, m0, 1, 0, A0b);
  STG(BT, n0, 0, 0, B0b); STG(BT, n0, 1, 0, B0b);
  STG(A, m0, 0, 1, A1b); STG(BT, n0, 0, 1, B1b);
  WVM(0);
  BAR();

  for (int T = 0; T + 2 < NT; T += 2) {
    LOAD_A(A0b, 0); LOAD_B(B0b, 0);
    STG(A, m0, 1, T + 1, A1b);
    BAR(); PRIO1(); MFMA16(0, 0); PRIO0(); BAR();
    LOAD_B(B0b, 2);
    STG(BT, n0, 1, T + 1, B1b);
    BAR(); PRIO1(); MFMA16(0, 2); PRIO0(); BAR();
    LOAD_A(A0b, 4);
    STG(BT, n0, 0, T + 2, B0b);
    BAR(); PRIO1(); MFMA16(4, 0); PRIO0(); BAR();
    STG(A, m0, 0, T + 2, A0b);
    WVM(4);
    BAR(); PRIO1(); MFMA16(4, 2); PRIO0(); BAR();
    LOAD_A(A1b, 0); LOAD_B(B1b, 0);
    STG(A, m0, 1, T + 2, A0b);
    BAR(); PRIO1(); MFMA16(0, 0); PRIO0(); BAR();
    LOAD_B(B1b, 2);
    STG(BT, n0, 1, T + 2, B0b);
    BAR(); PRIO1(); MFMA16(0, 2); PRIO0(); BAR();
    LOAD_A(A1b, 4);
    STG(BT, n0, 0, T + 3, B1b);
    BAR(); PRIO1(); MFMA16(4, 0); PRIO0(); BAR();
    STG(A, m0, 0, T + 3, A1b);
    WVM(4);
    BAR(); PRIO1(); MFMA16(4, 2); PRIO0(); BAR();
  }
  {
    int T = NT - 2;
    LOAD_A(A0b, 0); LOAD_B(B0b, 0);
    STG(A, m0, 1, T + 1, A1b);
    BAR(); PRIO1(); MFMA16(0, 0); PRIO0(); BAR();
    LOAD_B(B0b, 2);
    STG(BT, n0, 1, T + 1, B1b);
    BAR(); PRIO1(); MFMA16(0, 2); PRIO0(); BAR();
    LOAD_A(A0b, 4);
    BAR(); PRIO1(); MFMA16(4, 0); PRIO0(); BAR();
    WVM(0);
    BAR(); PRIO1(); MFMA16(4, 2); PRIO0(); BAR();
    LOAD_A(A1b, 0); LOAD_B(B1b, 0);
    BAR(); PRIO1(); MFMA16(0, 0); PRIO0(); BAR();
    LOAD_B(B1b, 2);
    BAR(); PRIO1(); MFMA16(0, 2); PRIO0(); BAR();
    LOAD_A(A1b, 4);
    BAR(); PRIO1(); MFMA16(4, 0); PRIO0(); BAR();
    PRIO1(); MFMA16(4, 2); PRIO0();
  }
#pragma unroll
  for (int mi = 0; mi < 8; ++mi) {
    int mrow = m0 + wr * 128 + mi * 16 + lg * 4;
#pragma unroll
    for (int ni = 0; ni < 4; ++ni) {
      int col = n0 + wc * 64 + ni * 16 + l15;
      float bv = bias[col];
#pragma unroll
      for (int j = 0; j < 4; ++j) {
        float v = acc[mi][ni][j] + bv;
        if (OUT_F32)
          ((float*)Cout)[(size_t)(mrow + j) * N + col] = v;
        else
          ((u16*)Cout)[(size_t)(mrow + j) * N + col] = f2bf(v);
      }
    }
  }
}

// ---------------- RoPE + scatter qkv -> q_pack [b][s][h][d] / k / v (bf16) ----------------
__global__ void rope_scatter(const u16* __restrict__ qkv, const float* __restrict__ freqs,
                             u16* __restrict__ qo, u16* __restrict__ ko, u16* __restrict__ vo) {
  const int per_row = QKVN / 8;  // 320
  const int total = B_ * S_ * per_row;
  int i = blockIdx.x * blockDim.x + threadIdx.x;
  int stride = gridDim.x * blockDim.x;
  for (; i < total; i += stride) {
    int m = i / per_row;
    int n8 = (i - m * per_row) * 8;
    int b = m >> 11, s = m & 2047;
    uint4 raw = *(const uint4*)(qkv + (size_t)m * QKVN + n8);
    const u16* u = (const u16*)&raw;
    if (n8 < 2304) {
      int d = (n8 < 2048) ? (n8 & 255) : (n8 - 2048);
      float scl = (n8 < 2048) ? (0.0625f * 1.44269504f) : 1.0f;
      const float* fp = freqs + ((size_t)s * 128 + (d >> 1)) * 2;
      float4 f0 = *(const float4*)fp;
      float4 f1 = *(const float4*)(fp + 4);
      float fc[8] = {f0.x, f0.y, f0.z, f0.w, f1.x, f1.y, f1.z, f1.w};
      u16 o[8];
#pragma unroll
      for (int p = 0; p < 4; ++p) {
        float r = bf2f(u[2 * p]), im = bf2f(u[2 * p + 1]);
        float c = fc[2 * p], sn = fc[2 * p + 1];
        o[2 * p] = f2bf((r * c - im * sn) * scl);
        o[2 * p + 1] = f2bf((r * sn + im * c) * scl);
      }
      u16* dst;
      if (n8 < 2048) {
        dst = qo + (size_t)m * 2048 + n8;  // packed [b][s][h][d]
      } else {
        dst = ko + (((size_t)m) << 8) + d;
      }
      *(uint4*)dst = *(const uint4*)o;
    } else {
      int d = n8 - 2304;
      *(uint4*)(vo + (((size_t)m) << 8) + d) = raw;
    }
  }
}

// ---------------- flash attention: 4-wave blocks (QBLK=128), 64KB LDS, 2 blocks/CU ----------------
// Registers cap waves at 8/CU (256 unified regs/wave); splitting them into TWO independent
// 4-wave blocks gives cross-block barrier overlap (block B computes while A drains staging).
// Per-wave datapath identical to R13-proven. Pairing (t, 127-t) + 2-way kv-split balances work.
// K LDS [64][512B] granule^=row&31; V paired rows [128][256B] granule^=r&15 (conflict-free).

#define STAGE_K1(kt)                                                                              \
  do {                                                                                            \
    _Pragma("unroll") for (int _p = 0; _p < 8; ++_p) {                                            \
      int _idx = _p * 256 + tid;                                                                  \
      int _row = _idx >> 5, _c = _idx & 31;                                                       \
      const u16* _src = Kp + ((size_t)(b * S_ + (kt) * 64 + _row)) * HD_ +                        \
                        ((_c ^ (_row & 31)) * 8);                                                 \
      __builtin_amdgcn_global_load_lds(                                                           \
          (const __attribute__((address_space(1))) void*)_src,                                    \
          (__attribute__((address_space(3))) void*)(KsBase + _idx * 8), 16, 0, 0);                \
    }                                                                                             \
  } while (0)

#define STAGE_V1(kt)                                                                              \
  do {                                                                                            \
    _Pragma("unroll") for (int _p = 0; _p < 8; ++_p) {                                            \
      int _idx = _p * 256 + tid;                                                                  \
      int _r = _idx >> 4, _gp = _idx & 15;                                                        \
      int _g = _gp ^ (_r & 15);                                                                   \
      int _d = _r * 2 + (_g >> 3), _c = _g & 7;                                                   \
      const u16* _src = VTp + ((size_t)(b * 256 + _d)) * S_ + (kt) * 64 + _c * 8;                 \
      __builtin_amdgcn_global_load_lds(                                                           \
          (const __attribute__((address_space(1))) void*)_src,                                    \
          (__attribute__((address_space(3))) void*)(VsBase + _idx * 8), 16, 0, 0);                \
    }                                                                                             \
  } while (0)

// Shared per-halftile compute (R13-proven datapath; smax = t*16+15 geometry handled by caller)
#define FLASH_TAU_BODY(Kbp, Vbp)                                                                  \
  do {                                                                                            \
    int row = tau * 32 + l31;                                                                     \
    f32x16 scv = {};                                                                              \
    __builtin_amdgcn_s_setprio(1);                                                                \
    _Pragma("unroll") for (int st = 0; st < 16; ++st) {                                           \
      bf16x8 kf = *(const bf16x8*)((Kbp) + row * 512 + (((st * 2 + lh) ^ l31) << 4));             \
      scv = __builtin_amdgcn_mfma_f32_32x32x16_bf16(kf, qf[st], scv, 0, 0, 0);                    \
    }                                                                                             \
    __builtin_amdgcn_s_setprio(0);                                                                \
    if (needmask) {                                                                               \
      _Pragma("unroll") for (int jj = 0; jj < 16; ++jj) {                                         \
        int kg = k0 + (jj & 3) + 8 * (jj >> 2) + 4 * lh;                                          \
        if (kg > s_g) scv[jj] = -3.0e38f;                                                         \
      }                                                                                           \
    }                                                                                             \
    float tmax = -3.0e38f;                                                                        \
    _Pragma("unroll") for (int jj = 0; jj < 16; ++jj) tmax = fmaxf(tmax, scv[jj]);                \
    tmax = fmaxf(tmax, __shfl_xor(tmax, 32));                                                     \
    if (!__all(tmax - m_r <= 8.0f)) {                                                             \
      float mnew = fmaxf(m_r, tmax);                                                              \
      float sc = exp2f(m_r - mnew);                                                               \
      l_r *= sc;                                                                                  \
      _Pragma("unroll") for (int dt = 0; dt < 8; ++dt) oacc[dt] *= sc;                            \
      m_r = mnew;                                                                                 \
    }                                                                                             \
    float ts = 0.f;                                                                               \
    unsigned cpk[8];                                                                              \
    _Pragma("unroll") for (int mi = 0; mi < 8; ++mi) {                                            \
      float p0 = exp2f(scv[2 * mi] - m_r);                                                        \
      float p1 = exp2f(scv[2 * mi + 1] - m_r);                                                    \
      ts += p0 + p1;                                                                              \
      cpk[mi] = ((unsigned)f2bf(p1) << 16) | f2bf(p0);                                            \
    }                                                                                             \
    ts += __shfl_xor(ts, 32);                                                                     \
    l_r += ts;                                                                                    \
    asm volatile("v_permlane32_swap_b32 %0, %1" : "+v"(cpk[0]), "+v"(cpk[2]));                    \
    asm volatile("v_permlane32_swap_b32 %0, %1" : "+v"(cpk[1]), "+v"(cpk[3]));                    \
    asm volatile("v_permlane32_swap_b32 %0, %1" : "+v"(cpk[4]), "+v"(cpk[6]));                    \
    asm volatile("v_permlane32_swap_b32 %0, %1" : "+v"(cpk[5]), "+v"(cpk[7]));                    \
    union { unsigned u[4]; bf16x8 v; } pa, pb;                                                    \
    pa.u[0] = cpk[0]; pa.u[1] = cpk[1]; pa.u[2] = cpk[2]; pa.u[3] = cpk[3];                       \
    pb.u[0] = cpk[4]; pb.u[1] = cpk[5]; pb.u[2] = cpk[6]; pb.u[3] = cpk[7];                       \
    __builtin_amdgcn_s_setprio(1);                                                                \
    _Pragma("unroll") for (int dt = 0; dt < 8; ++dt) {                                            \
      int d = dt * 32 + l31;                                                                      \
      int rr = d >> 1;                                                                            \
      int gb = (d & 1) * 8 + tau * 4;                                                             \
      int rx = (rr & 15) << 4;                                                                    \
      bf16x8 va = *(const bf16x8*)((Vbp) + rr * 256 + (((gb + lh) << 4) ^ rx));                   \
      oacc[dt] = __builtin_amdgcn_mfma_f32_32x32x16_bf16(va, pa.v, oacc[dt], 0, 0, 0);            \
      bf16x8 vb2 = *(const bf16x8*)((Vbp) + rr * 256 + (((gb + 2 + lh) << 4) ^ rx));              \
      oacc[dt] = __builtin_amdgcn_mfma_f32_32x32x16_bf16(vb2, pb.v, oacc[dt], 0, 0, 0);           \
    }                                                                                             \
    __builtin_amdgcn_s_setprio(0);                                                                \
  } while (0)

__global__ __launch_bounds__(256, 2) void flash_attn_split(const u16* __restrict__ Qp, const u16* __restrict__ Kp,
                                                           const u16* __restrict__ VTp, u16* __restrict__ P0,
                                                           float* __restrict__ ml0, float* __restrict__ ml1,
                                                           u16* __restrict__ Op) {
  __shared__ u16 Ks[64 * 256];   // 32 KB
  __shared__ u16 Vs[128 * 128];  // 32 KB
  int bid = (int)blockIdx.x;     // grid 512
  int b = (bid & 7) >> 1;        // XCD-pair -> batch (K/V L2 locality)
  int part = bid & 1;
  int pair = bid >> 3;           // 0..63
  int tid = threadIdx.x;
  int w = tid >> 6, l = tid & 63;
  int l31 = l & 31, lh = l >> 5;
  int q_local = w * 32 + l31;    // 0..127
  u16* KsBase = &Ks[0];
  u16* VsBase = &Vs[0];
  float* mlbuf = part ? ml1 : ml0;

  for (int seg = 0; seg < 2; ++seg) {
    int t = seg ? (127 - pair) : pair;      // QBLK=128 rows = 16 s x 8 heads
    int nkv = (t >> 2) + 1;                 // kt tiles of 64 k
    int half = (nkv + 1) >> 1;
    int kb = part ? half : 0;
    int ke = part ? nkv : half;
    size_t qrow = (size_t)b * 16384 + (size_t)t * 128 + q_local;
    int s_g = t * 16 + (q_local >> 3);
    int smin = t * 16, smax = t * 16 + 15;
    if (kb >= ke) {
      if (lh == 0) { mlbuf[qrow * 2] = -3.0e38f; mlbuf[qrow * 2 + 1] = 0.f; }
      continue;
    }
    bf16x8 qf[16];
    const u16* qp = Qp + qrow * HD_ + lh * 8;
#pragma unroll
    for (int st = 0; st < 16; ++st) qf[st] = *(const bf16x8*)(qp + st * 16);
    f32x16 oacc[8] = {};
    float m_r = -3.0e38f, l_r = 0.f;

    STAGE_K1(kb);
    STAGE_V1(kb);
    __syncthreads();
    for (int kt = kb; kt < ke; ++kt) {
#pragma unroll
      for (int tau = 0; tau < 2; ++tau) {
        int k0 = kt * 64 + tau * 32;
        if (k0 > smax) break;               // fully-masked half-tile (block-uniform)
        bool needmask = (k0 + 31 > smin);
        FLASH_TAU_BODY((const char*)KsBase, (const char*)VsBase);
      }
      __syncthreads();
      if (kt + 1 < ke) {
        STAGE_K1(kt + 1);
        STAGE_V1(kt + 1);
        __syncthreads();
      }
    }

    float inv = 1.0f / l_r;
    u16* ob = (part ? Op : P0) + qrow * 256;
#pragma unroll
    for (int dt = 0; dt < 8; ++dt) {
#pragma unroll
      for (int jj = 0; jj < 4; ++jj) {
        int d0 = dt * 32 + jj * 8 + 4 * lh;
        u16 o4[4];
#pragma unroll
        for (int e = 0; e < 4; ++e) o4[e] = f2bf(oacc[dt][jj * 4 + e] * inv);
        *(ull*)(ob + d0) = *(const ull*)o4;
      }
    }
    if (lh == 0) { mlbuf[qrow * 2] = m_r; mlbuf[qrow * 2 + 1] = l_r; }
  }
}

// ---------------- combine (coalesced): thread = (row, 16B col chunk) ----------------
__global__ __launch_bounds__(256) void combine_parts(const u16* __restrict__ P0, const float* __restrict__ ml0,
                                                     const float* __restrict__ ml1, u16* __restrict__ O) {
  int idx = blockIdx.x * 256 + threadIdx.x;  // 65536 rows * 32 chunks
  int r = idx >> 5;
  int c = (idx & 31) * 8;
  float m0 = ml0[(size_t)r * 2], l0 = ml0[(size_t)r * 2 + 1];
  float m1 = ml1[(size_t)r * 2], l1 = ml1[(size_t)r * 2 + 1];
  float M = fmaxf(m0, m1);
  float w0 = l0 * exp2f(m0 - M), w1 = l1 * exp2f(m1 - M);
  float inv = 1.0f / (w0 + w1);
  w0 *= inv; w1 *= inv;
  uint4 a = *(const uint4*)(P0 + (size_t)r * 256 + c);
  uint4 bq = *(const uint4*)(O + (size_t)r * 256 + c);
  const u16* ua = (const u16*)&a;
  const u16* ub = (const u16*)&bq;
  u16 o[8];
#pragma unroll
  for (int e = 0; e < 8; ++e) o[e] = f2bf(w0 * bf2f(ua[e]) + w1 * bf2f(ub[e]));
  *(uint4*)(O + (size_t)r * 256 + c) = *(const uint4*)o;
}

extern "C" void kernel_launch(void* const* d_in, const int* in_sizes, int n_in,
                              void* d_out, int out_size, void* d_ws, size_t ws_size,
                              hipStream_t stream) {
  const float* x = (const float*)d_in[0];
  const float* w_qkv = (const float*)d_in[1];
  const float* b_qkv = (const float*)d_in[2];
  const float* w_o = (const float*)d_in[3];
  const float* b_o = (const float*)d_in[4];
  const float* freqs = (const float*)d_in[5];
  // d_in[6] is the causal mask; causality is implemented directly.

  char* ws = (char*)d_ws;
  u16* xb    = (u16*)ws;                          // 33,554,432 B
  u16* wqkvT = (u16*)(ws + 33554432);             // 10,485,760 B
  u16* woT   = (u16*)(ws + 44040192);             //  8,388,608 B
  u16* qkv   = (u16*)(ws + 52428800);             // 41,943,040 B
  u16* qall  = (u16*)(ws + 94371840);             // 33,554,432 B
  u16* kbuf  = (u16*)(ws + 127926272);            //  4,194,304 B
  u16* vbuf  = (u16*)(ws + 132120576);            //  4,194,304 B
  u16* part0 = (u16*)(ws + 136314880);            // 33,554,432 B
  float* ml0 = (float*)(ws + 169869312);          //    524,288 B
  float* ml1 = (float*)(ws + 170393600);          //    524,288 B  -> need 170,917,888
  u16* vT    = xb;    // alias: xb dead after QKV GEMM
  u16* attout = qkv;  // alias: qkv dead after rope_scatter

  cast_f32_bf16<<<2048, 256, 0, stream>>>(x, xb, (B_ * S_ * HID_) / 8);
  transpose_cast<<<dim3(QKVN / 32, HID_ / 32), dim3(32, 8), 0, stream>>>(w_qkv, wqkvT, HID_, QKVN);
  transpose_cast<<<dim3(HID_ / 32, HID_ / 32), dim3(32, 8), 0, stream>>>(w_o, woT, HID_, HID_);
  gemm256<false><<<dim3(32 * 10), 512, 0, stream>>>(xb, wqkvT, b_qkv, qkv, B_ * S_, QKVN, HID_);
  rope_scatter<<<2048, 256, 0, stream>>>(qkv, freqs, qall, kbuf, vbuf);
  transpose_bf16<<<dim3(HD_ / 32, S_ / 32, B_), dim3(32, 8), 0, stream>>>(vbuf, vT, S_, HD_);
  flash_attn_split<<<512, 256, 0, stream>>>(qall, kbuf, vT, part0, ml0, ml1, attout);
  combine_parts<<<8192, 256, 0, stream>>>(part0, ml0, ml1, attout);
  gemm256<true><<<dim3(32 * 8), 512, 0, stream>>>(attout, woT, b_o, d_out, B_ * S_, HID_, HID_);
}

// Round 17
// 395.918 us; speedup vs baseline: 1.2750x; 1.2750x over previous
//
#include <hip/hip_runtime.h>
#include <hip/hip_bf16.h>

#define B_ 4
#define S_ 2048
#define HID_ 2048
#define NH_ 8
#define HD_ 256
#define QKVN 2560

typedef unsigned short u16;
typedef unsigned long long ull;
typedef __attribute__((ext_vector_type(4))) float f32x4;
typedef __attribute__((ext_vector_type(16))) float f32x16;
typedef __attribute__((ext_vector_type(8))) short bf16x8;

__device__ __forceinline__ float bf2f(u16 u) {
  union { unsigned int i; float f; } v; v.i = ((unsigned int)u) << 16; return v.f;
}
__device__ __forceinline__ u16 f2bf(float f) {
  union { unsigned int i; float f; } v; v.f = f;
  unsigned int r = v.i + 0x7fffu + ((v.i >> 16) & 1u);
  return (u16)(r >> 16);
}

// ---------------- cast x (f32 -> bf16), 8 elems/thread ----------------
__global__ void cast_f32_bf16(const float* __restrict__ in, u16* __restrict__ out, int n8) {
  int i = blockIdx.x * blockDim.x + threadIdx.x;
  int stride = gridDim.x * blockDim.x;
  for (; i < n8; i += stride) {
    const float4* p = (const float4*)(in + (size_t)i * 8);
    float4 a = p[0], b = p[1];
    u16 o[8] = {f2bf(a.x), f2bf(a.y), f2bf(a.z), f2bf(a.w),
                f2bf(b.x), f2bf(b.y), f2bf(b.z), f2bf(b.w)};
    *(uint4*)(out + (size_t)i * 8) = *(const uint4*)o;
  }
}

// ------------- transpose + cast: in[R][C] f32 -> out[C][R] bf16 -------------
__global__ void transpose_cast(const float* __restrict__ in, u16* __restrict__ out, int R, int C) {
  __shared__ float t[32][33];
  int c0 = blockIdx.x * 32, r0 = blockIdx.y * 32;
  int tx = threadIdx.x, ty = threadIdx.y;
#pragma unroll
  for (int i = 0; i < 4; ++i)
    t[ty + i * 8][tx] = in[(size_t)(r0 + ty + i * 8) * C + c0 + tx];
  __syncthreads();
#pragma unroll
  for (int i = 0; i < 4; ++i)
    out[(size_t)(c0 + ty + i * 8) * R + r0 + tx] = f2bf(t[tx][ty + i * 8]);
}

// ------------- transpose bf16 (per-batch): in[R][C] -> out[C][R] -------------
__global__ void transpose_bf16(const u16* __restrict__ in, u16* __restrict__ out, int R, int C) {
  __shared__ u16 t[32][33];
  in += (size_t)blockIdx.z * R * C;
  out += (size_t)blockIdx.z * R * C;
  int c0 = blockIdx.x * 32, r0 = blockIdx.y * 32;
  int tx = threadIdx.x, ty = threadIdx.y;
#pragma unroll
  for (int i = 0; i < 4; ++i)
    t[ty + i * 8][tx] = in[(size_t)(r0 + ty + i * 8) * C + c0 + tx];
  __syncthreads();
#pragma unroll
  for (int i = 0; i < 4; ++i)
    out[(size_t)(c0 + ty + i * 8) * R + r0 + tx] = t[tx][ty + i * 8];
}

// ================= shared GEMM helpers =================
#define BAR() __builtin_amdgcn_s_barrier()
#define PRIO1() __builtin_amdgcn_s_setprio(1)
#define PRIO0() __builtin_amdgcn_s_setprio(0)
#define SB0() __builtin_amdgcn_sched_barrier(0)
#define WVM(n)                                                                                    \
  do {                                                                                            \
    SB0();                                                                                        \
    asm volatile("s_waitcnt vmcnt(" #n ")" ::: "memory");                                         \
    SB0();                                                                                        \
  } while (0)

// stage 128 rows x 64 cols (2 loads/thread @512 threads)
#define STG(mat, b0, h, T, ldsb)                                                                  \
  do {                                                                                            \
    _Pragma("unroll") for (int q = 0; q < 2; ++q) {                                               \
      int idx = q * 512 + tid;                                                                    \
      int rl = idx >> 3, gp = idx & 7;                                                            \
      const u16* s = (mat) + (size_t)((b0) + (h) * 128 + rl) * K + (T) * 64 +                     \
                     ((gp ^ (rl & 7)) << 3);                                                      \
      __builtin_amdgcn_global_load_lds((const __attribute__((address_space(1))) void*)s,          \
          (__attribute__((address_space(3))) void*)((ldsb) + (h) * 8192 + idx * 8), 16, 0, 0);    \
    }                                                                                             \
  } while (0)

// stage 64 rows x 64 cols (1 load/thread @512 threads)
#define STGH(mat, b0, h, T, ldsb)                                                                 \
  do {                                                                                            \
    int idx = tid;                                                                                \
    int rl = idx >> 3, gp = idx & 7;                                                              \
    const u16* s = (mat) + (size_t)((b0) + (h) * 64 + rl) * K + (T) * 64 +                        \
                   ((gp ^ (rl & 7)) << 3);                                                        \
    __builtin_amdgcn_global_load_lds((const __attribute__((address_space(1))) void*)s,            \
        (__attribute__((address_space(3))) void*)((ldsb) + (h) * 4096 + idx * 8), 16, 0, 0);      \
  } while (0)

// ================= 256x256 8-phase GEMM (R10-proven; used for proj) =================
#define LOAD_A(buf, mib)                                                                          \
  _Pragma("unroll") for (int mi = 0; mi < 4; ++mi)                                                \
  _Pragma("unroll") for (int ks = 0; ks < 2; ++ks)                                                \
    af[mi][ks] = *(const bf16x8*)((buf) + (wr * 128 + ((mib) + mi) * 16 + l15) * 64 +             \
                                  (((ks * 4 + lg) ^ (l15 & 7)) << 3));

#define LOAD_B(buf, nib)                                                                          \
  _Pragma("unroll") for (int ni = 0; ni < 2; ++ni)                                                \
  _Pragma("unroll") for (int ks = 0; ks < 2; ++ks)                                                \
    bfr[(nib) + ni][ks] = *(const bf16x8*)((buf) + (wc * 64 + ((nib) + ni) * 16 + l15) * 64 +     \
                                           (((ks * 4 + lg) ^ (l15 & 7)) << 3));

#define MFMA16(accb, nib)                                                                         \
  _Pragma("unroll") for (int mi = 0; mi < 4; ++mi)                                                \
  _Pragma("unroll") for (int ni = 0; ni < 2; ++ni)                                                \
  _Pragma("unroll") for (int ks = 0; ks < 2; ++ks)                                                \
    acc[(accb) + mi][(nib) + ni] = __builtin_amdgcn_mfma_f32_16x16x32_bf16(                       \
        af[mi][ks], bfr[(nib) + ni][ks], acc[(accb) + mi][(nib) + ni], 0, 0, 0);

template <bool OUT_F32>
__global__ __launch_bounds__(512, 2) void gemm256(const u16* __restrict__ A, const u16* __restrict__ BT,
                                                  const float* __restrict__ bias, void* __restrict__ Cout,
                                                  int M, int N, int K) {
  __shared__ u16 Asm[2][16384];
  __shared__ u16 Bsm[2][16384];
  int nwg = gridDim.x;
  int bid = (int)blockIdx.x;
  bid = (bid & 7) * (nwg >> 3) + (bid >> 3);  // XCD swizzle (nwg % 8 == 0)
  int ntn = N >> 8;
  int m0 = (bid / ntn) << 8, n0 = (bid % ntn) << 8;
  int tid = threadIdx.x, w = tid >> 6, lane = tid & 63;
  int wr = w >> 2, wc = w & 3;
  int l15 = lane & 15, lg = lane >> 4;
  int NT = K >> 6;
  u16* A0b = &Asm[0][0]; u16* A1b = &Asm[1][0];
  u16* B0b = &Bsm[0][0]; u16* B1b = &Bsm[1][0];
  f32x4 acc[8][4] = {};
  bf16x8 af[4][2], bfr[4][2];

  STG(A, m0, 0, 0, A0b); STG(A, m0, 1, 0, A0b);
  STG(BT, n0, 0, 0, B0b); STG(BT, n0, 1, 0, B0b);
  STG(A, m0, 0, 1, A1b); STG(BT, n0, 0, 1, B1b);
  WVM(0);
  BAR();

  for (int T = 0; T + 2 < NT; T += 2) {
    LOAD_A(A0b, 0); LOAD_B(B0b, 0);
    STG(A, m0, 1, T + 1, A1b);
    BAR(); PRIO1(); MFMA16(0, 0); PRIO0(); BAR();
    LOAD_B(B0b, 2);
    STG(BT, n0, 1, T + 1, B1b);
    BAR(); PRIO1(); MFMA16(0, 2); PRIO0(); BAR();
    LOAD_A(A0b, 4);
    STG(BT, n0, 0, T + 2, B0b);
    BAR(); PRIO1(); MFMA16(4, 0); PRIO0(); BAR();
    STG(A, m0, 0, T + 2, A0b);
    WVM(4);
    BAR(); PRIO1(); MFMA16(4, 2); PRIO0(); BAR();
    LOAD_A(A1b, 0); LOAD_B(B1b, 0);
    STG(A, m0, 1, T + 2, A0b);
    BAR(); PRIO1(); MFMA16(0, 0); PRIO0(); BAR();
    LOAD_B(B1b, 2);
    STG(BT, n0, 1, T + 2, B0b);
    BAR(); PRIO1(); MFMA16(0, 2); PRIO0(); BAR();
    LOAD_A(A1b, 4);
    STG(BT, n0, 0, T + 3, B1b);
    BAR(); PRIO1(); MFMA16(4, 0); PRIO0(); BAR();
    STG(A, m0, 0, T + 3, A1b);
    WVM(4);
    BAR(); PRIO1(); MFMA16(4, 2); PRIO0(); BAR();
  }
  {
    int T = NT - 2;
    LOAD_A(A0b, 0); LOAD_B(B0b, 0);
    STG(A, m0, 1, T + 1, A1b);
    BAR(); PRIO1(); MFMA16(0, 0); PRIO0(); BAR();
    LOAD_B(B0b, 2);
    STG(BT, n0, 1, T + 1, B1b);
    BAR(); PRIO1(); MFMA16(0, 2); PRIO0(); BAR();
    LOAD_A(A0b, 4);
    BAR(); PRIO1(); MFMA16(4, 0); PRIO0(); BAR();
    WVM(0);
    BAR(); PRIO1(); MFMA16(4, 2); PRIO0(); BAR();
    LOAD_A(A1b, 0); LOAD_B(B1b, 0);
    BAR(); PRIO1(); MFMA16(0, 0); PRIO0(); BAR();
    LOAD_B(B1b, 2);
    BAR(); PRIO1(); MFMA16(0, 2); PRIO0(); BAR();
    LOAD_A(A1b, 4);
    BAR(); PRIO1(); MFMA16(4, 0); PRIO0(); BAR();
    PRIO1(); MFMA16(4, 2); PRIO0();
  }
#pragma unroll
  for (int mi = 0; mi < 8; ++mi) {
    int mrow = m0 + wr * 128 + mi * 16 + lg * 4;
#pragma unroll
    for (int ni = 0; ni < 4; ++ni) {
      int col = n0 + wc * 64 + ni * 16 + l15;
      float bv = bias[col];
#pragma unroll
      for (int j = 0; j < 4; ++j) {
        float v = acc[mi][ni][j] + bv;
        if (OUT_F32)
          ((float*)Cout)[(size_t)(mrow + j) * N + col] = v;
        else
          ((u16*)Cout)[(size_t)(mrow + j) * N + col] = f2bf(v);
      }
    }
  }
}

// ========== 256x128 8-phase GEMM (same template, BN=128; used for QKV: grid 640) ==========
// 8 waves as 4M x 2N, per-wave 64x64. B tile 128x64: staged as two 64-row STGH halves so
// the per-phase stage cadence is preserved; counted checkpoints become WVM(3)
// (6 loads/tile: at P4/P8 keep newest 3 = the T+2 stages, drain tile T+1).
#define LOAD_A2(buf, mib)                                                                         \
  _Pragma("unroll") for (int mi = 0; mi < 2; ++mi)                                                \
  _Pragma("unroll") for (int ks = 0; ks < 2; ++ks)                                                \
    af2[mi][ks] = *(const bf16x8*)((buf) + (wr4 * 64 + ((mib) + mi) * 16 + l15) * 64 +            \
                                   (((ks * 4 + lg) ^ (l15 & 7)) << 3));

#define LOAD_B2(buf, nib)                                                                         \
  _Pragma("unroll") for (int ni = 0; ni < 2; ++ni)                                                \
  _Pragma("unroll") for (int ks = 0; ks < 2; ++ks)                                                \
    bfr2[(nib) + ni][ks] = *(const bf16x8*)((buf) + (wc2 * 64 + ((nib) + ni) * 16 + l15) * 64 +   \
                                            (((ks * 4 + lg) ^ (l15 & 7)) << 3));

#define MFMA8(accb, nib)                                                                          \
  _Pragma("unroll") for (int mi = 0; mi < 2; ++mi)                                                \
  _Pragma("unroll") for (int ni = 0; ni < 2; ++ni)                                                \
  _Pragma("unroll") for (int ks = 0; ks < 2; ++ks)                                                \
    acc2[(accb) + mi][(nib) + ni] = __builtin_amdgcn_mfma_f32_16x16x32_bf16(                      \
        af2[mi][ks], bfr2[(nib) + ni][ks], acc2[(accb) + mi][(nib) + ni], 0, 0, 0);

__global__ __launch_bounds__(512, 2) void gemm256n128(const u16* __restrict__ A, const u16* __restrict__ BT,
                                                      const float* __restrict__ bias, u16* __restrict__ Cout,
                                                      int M, int N, int K) {
  __shared__ u16 Asm2[2][16384];  // 2 x 32KB
  __shared__ u16 Bsm2[2][8192];   // 2 x 16KB
  int nwg = gridDim.x;
  int bid = (int)blockIdx.x;
  bid = (bid & 7) * (nwg >> 3) + (bid >> 3);  // XCD swizzle (nwg % 8 == 0)
  int ntn = N >> 7;
  int m0 = (bid / ntn) << 8, n0 = (bid % ntn) << 7;
  int tid = threadIdx.x, w = tid >> 6, lane = tid & 63;
  int wr4 = w >> 1, wc2 = w & 1;  // 4M x 2N waves
  int l15 = lane & 15, lg = lane >> 4;
  int NT = K >> 6;
  u16* A0b = &Asm2[0][0]; u16* A1b = &Asm2[1][0];
  u16* B0b = &Bsm2[0][0]; u16* B1b = &Bsm2[1][0];
  f32x4 acc2[4][4] = {};
  bf16x8 af2[2][2], bfr2[4][2];

  // prologue: tile0 full + A(h0,1), B(h0,1)
  STG(A, m0, 0, 0, A0b); STG(A, m0, 1, 0, A0b);
  STGH(BT, n0, 0, 0, B0b); STGH(BT, n0, 1, 0, B0b);
  STG(A, m0, 0, 1, A1b); STGH(BT, n0, 0, 1, B1b);
  WVM(0);
  BAR();

  for (int T = 0; T + 2 < NT; T += 2) {
    LOAD_A2(A0b, 0); LOAD_B2(B0b, 0);
    STG(A, m0, 1, T + 1, A1b);
    BAR(); PRIO1(); MFMA8(0, 0); PRIO0(); BAR();
    LOAD_B2(B0b, 2);
    STGH(BT, n0, 1, T + 1, B1b);
    BAR(); PRIO1(); MFMA8(0, 2); PRIO0(); BAR();
    LOAD_A2(A0b, 2);
    STGH(BT, n0, 0, T + 2, B0b);
    BAR(); PRIO1(); MFMA8(2, 0); PRIO0(); BAR();
    STG(A, m0, 0, T + 2, A0b);
    WVM(3);
    BAR(); PRIO1(); MFMA8(2, 2); PRIO0(); BAR();
    LOAD_A2(A1b, 0); LOAD_B2(B1b, 0);
    STG(A, m0, 1, T + 2, A0b);
    BAR(); PRIO1(); MFMA8(0, 0); PRIO0(); BAR();
    LOAD_B2(B1b, 2);
    STGH(BT, n0, 1, T + 2, B0b);
    BAR(); PRIO1(); MFMA8(0, 2); PRIO0(); BAR();
    LOAD_A2(A1b, 2);
    STGH(BT, n0, 0, T + 3, B1b);
    BAR(); PRIO1(); MFMA8(2, 0); PRIO0(); BAR();
    STG(A, m0, 0, T + 3, A1b);
    WVM(3);
    BAR(); PRIO1(); MFMA8(2, 2); PRIO0(); BAR();
  }
  {  // epilogue: tiles NT-2, NT-1
    int T = NT - 2;
    LOAD_A2(A0b, 0); LOAD_B2(B0b, 0);
    STG(A, m0, 1, T + 1, A1b);
    BAR(); PRIO1(); MFMA8(0, 0); PRIO0(); BAR();
    LOAD_B2(B0b, 2);
    STGH(BT, n0, 1, T + 1, B1b);
    BAR(); PRIO1(); MFMA8(0, 2); PRIO0(); BAR();
    LOAD_A2(A0b, 2);
    BAR(); PRIO1(); MFMA8(2, 0); PRIO0(); BAR();
    WVM(0);
    BAR(); PRIO1(); MFMA8(2, 2); PRIO0(); BAR();
    LOAD_A2(A1b, 0); LOAD_B2(B1b, 0);
    BAR(); PRIO1(); MFMA8(0, 0); PRIO0(); BAR();
    LOAD_B2(B1b, 2);
    BAR(); PRIO1(); MFMA8(0, 2); PRIO0(); BAR();
    LOAD_A2(A1b, 2);
    BAR(); PRIO1(); MFMA8(2, 0); PRIO0(); BAR();
    PRIO1(); MFMA8(2, 2); PRIO0();
  }
#pragma unroll
  for (int mi = 0; mi < 4; ++mi) {
    int mrow = m0 + wr4 * 64 + mi * 16 + lg * 4;
#pragma unroll
    for (int ni = 0; ni < 4; ++ni) {
      int col = n0 + wc2 * 64 + ni * 16 + l15;
      float bv = bias[col];
#pragma unroll
      for (int j = 0; j < 4; ++j)
        Cout[(size_t)(mrow + j) * N + col] = f2bf(acc2[mi][ni][j] + bv);
    }
  }
}

// ---------------- RoPE + scatter qkv -> q_pack [b][s][h][d] / k / v (bf16) ----------------
__global__ void rope_scatter(const u16* __restrict__ qkv, const float* __restrict__ freqs,
                             u16* __restrict__ qo, u16* __restrict__ ko, u16* __restrict__ vo) {
  const int per_row = QKVN / 8;  // 320
  const int total = B_ * S_ * per_row;
  int i = blockIdx.x * blockDim.x + threadIdx.x;
  int stride = gridDim.x * blockDim.x;
  for (; i < total; i += stride) {
    int m = i / per_row;
    int n8 = (i - m * per_row) * 8;
    int b = m >> 11, s = m & 2047;
    uint4 raw = *(const uint4*)(qkv + (size_t)m * QKVN + n8);
    const u16* u = (const u16*)&raw;
    if (n8 < 2304) {
      int d = (n8 < 2048) ? (n8 & 255) : (n8 - 2048);
      float scl = (n8 < 2048) ? (0.0625f * 1.44269504f) : 1.0f;
      const float* fp = freqs + ((size_t)s * 128 + (d >> 1)) * 2;
      float4 f0 = *(const float4*)fp;
      float4 f1 = *(const float4*)(fp + 4);
      float fc[8] = {f0.x, f0.y, f0.z, f0.w, f1.x, f1.y, f1.z, f1.w};
      u16 o[8];
#pragma unroll
      for (int p = 0; p < 4; ++p) {
        float r = bf2f(u[2 * p]), im = bf2f(u[2 * p + 1]);
        float c = fc[2 * p], sn = fc[2 * p + 1];
        o[2 * p] = f2bf((r * c - im * sn) * scl);
        o[2 * p + 1] = f2bf((r * sn + im * c) * scl);
      }
      u16* dst;
      if (n8 < 2048) {
        dst = qo + (size_t)m * 2048 + n8;  // packed [b][s][h][d]
      } else {
        dst = ko + (((size_t)m) << 8) + d;
      }
      *(uint4*)dst = *(const uint4*)o;
    } else {
      int d = n8 - 2304;
      *(uint4*)(vo + (((size_t)m) << 8) + d) = raw;
    }
  }
}

// ---------------- flash attention core (R13-proven, reverted) ----------------
#define STAGE_K(bufofs, kt)                                                                       \
  do {                                                                                            \
    _Pragma("unroll") for (int _p = 0; _p < 4; ++_p) {                                            \
      int _idx = _p * 512 + tid;                                                                  \
      int _row = _idx >> 5, _c = _idx & 31;                                                       \
      const u16* _src = Kp + ((size_t)(b * S_ + (kt) * 64 + _row)) * HD_ +                        \
                        ((_c ^ (_row & 31)) * 8);                                                 \
      __builtin_amdgcn_global_load_lds(                                                           \
          (const __attribute__((address_space(1))) void*)_src,                                    \
          (__attribute__((address_space(3))) void*)(KsBase + (bufofs) + _idx * 8), 16, 0, 0);     \
    }                                                                                             \
  } while (0)

#define STAGE_V(bufofs, kt)                                                                       \
  do {                                                                                            \
    _Pragma("unroll") for (int _p = 0; _p < 4; ++_p) {                                            \
      int _idx = _p * 512 + tid;                                                                  \
      int _r = _idx >> 4, _gp = _idx & 15;                                                        \
      int _g = _gp ^ (_r & 15);                                                                   \
      int _d = _r * 2 + (_g >> 3), _c = _g & 7;                                                   \
      const u16* _src = VTp + ((size_t)(b * 256 + _d)) * S_ + (kt) * 64 + _c * 8;                 \
      __builtin_amdgcn_global_load_lds(                                                           \
          (const __attribute__((address_space(1))) void*)_src,                                    \
          (__attribute__((address_space(3))) void*)(VsBase + (bufofs) + _idx * 8), 16, 0, 0);     \
    }                                                                                             \
  } while (0)

#define FLASH_SEG_BODY()                                                                          \
  STAGE_K(0, kb);                                                                                 \
  STAGE_V(0, kb);                                                                                 \
  __syncthreads();                                                                                \
  int cur = 0;                                                                                    \
  for (int kt = kb; kt < ke; ++kt) {                                                              \
    if (kt + 1 < ke) {                                                                            \
      STAGE_K((cur ^ 1) * 16384, kt + 1);                                                         \
      STAGE_V((cur ^ 1) * 16384, kt + 1);                                                         \
    }                                                                                             \
    const char* Kb = (const char*)(KsBase + cur * 16384);                                         \
    const char* Vb = (const char*)(VsBase + cur * 16384);                                         \
    _Pragma("unroll") for (int tau = 0; tau < 2; ++tau) {                                         \
      int k0 = kt * 64 + tau * 32;                                                                \
      if (k0 > t * 32 + 31) break;                                                                \
      int row = tau * 32 + l31;                                                                   \
      f32x16 scv = {};                                                                            \
      __builtin_amdgcn_s_setprio(1);                                                              \
      _Pragma("unroll") for (int st = 0; st < 16; ++st) {                                         \
        bf16x8 kf = *(const bf16x8*)(Kb + row * 512 + (((st * 2 + lh) ^ l31) << 4));              \
        scv = __builtin_amdgcn_mfma_f32_32x32x16_bf16(kf, qf[st], scv, 0, 0, 0);                  \
      }                                                                                           \
      __builtin_amdgcn_s_setprio(0);                                                              \
      if (k0 + 31 > t * 32) {                                                                     \
        _Pragma("unroll") for (int jj = 0; jj < 16; ++jj) {                                       \
          int kg = k0 + (jj & 3) + 8 * (jj >> 2) + 4 * lh;                                        \
          if (kg > s_g) scv[jj] = -3.0e38f;                                                       \
        }                                                                                         \
      }                                                                                           \
      float tmax = -3.0e38f;                                                                      \
      _Pragma("unroll") for (int jj = 0; jj < 16; ++jj) tmax = fmaxf(tmax, scv[jj]);              \
      tmax = fmaxf(tmax, __shfl_xor(tmax, 32));                                                   \
      if (!__all(tmax - m_r <= 8.0f)) {                                                           \
        float mnew = fmaxf(m_r, tmax);                                                            \
        float sc = exp2f(m_r - mnew);                                                             \
        l_r *= sc;                                                                                \
        _Pragma("unroll") for (int dt = 0; dt < 8; ++dt) oacc[dt] *= sc;                          \
        m_r = mnew;                                                                               \
      }                                                                                           \
      float ts = 0.f;                                                                             \
      unsigned cpk[8];                                                                            \
      _Pragma("unroll") for (int mi = 0; mi < 8; ++mi) {                                          \
        float p0 = exp2f(scv[2 * mi] - m_r);                                                      \
        float p1 = exp2f(scv[2 * mi + 1] - m_r);                                                  \
        ts += p0 + p1;                                                                            \
        cpk[mi] = ((unsigned)f2bf(p1) << 16) | f2bf(p0);                                          \
      }                                                                                           \
      ts += __shfl_xor(ts, 32);                                                                   \
      l_r += ts;                                                                                  \
      asm volatile("v_permlane32_swap_b32 %0, %1" : "+v"(cpk[0]), "+v"(cpk[2]));                  \
      asm volatile("v_permlane32_swap_b32 %0, %1" : "+v"(cpk[1]), "+v"(cpk[3]));                  \
      asm volatile("v_permlane32_swap_b32 %0, %1" : "+v"(cpk[4]), "+v"(cpk[6]));                  \
      asm volatile("v_permlane32_swap_b32 %0, %1" : "+v"(cpk[5]), "+v"(cpk[7]));                  \
      union { unsigned u[4]; bf16x8 v; } pa, pb;                                                  \
      pa.u[0] = cpk[0]; pa.u[1] = cpk[1]; pa.u[2] = cpk[2]; pa.u[3] = cpk[3];                     \
      pb.u[0] = cpk[4]; pb.u[1] = cpk[5]; pb.u[2] = cpk[6]; pb.u[3] = cpk[7];                     \
      __builtin_amdgcn_s_setprio(1);                                                              \
      _Pragma("unroll") for (int dt = 0; dt < 8; ++dt) {                                          \
        int d = dt * 32 + l31;                                                                    \
        int rr = d >> 1;                                                                          \
        int gb = (d & 1) * 8 + tau * 4;                                                           \
        int rx = (rr & 15) << 4;                                                                  \
        bf16x8 va = *(const bf16x8*)(Vb + rr * 256 + (((gb + lh) << 4) ^ rx));                    \
        oacc[dt] = __builtin_amdgcn_mfma_f32_32x32x16_bf16(va, pa.v, oacc[dt], 0, 0, 0);          \
        bf16x8 vb2 = *(const bf16x8*)(Vb + rr * 256 + (((gb + 2 + lh) << 4) ^ rx));               \
        oacc[dt] = __builtin_amdgcn_mfma_f32_32x32x16_bf16(vb2, pb.v, oacc[dt], 0, 0, 0);         \
      }                                                                                           \
      __builtin_amdgcn_s_setprio(0);                                                              \
    }                                                                                             \
    __syncthreads();                                                                              \
    cur ^= 1;                                                                                     \
  }

__global__ __launch_bounds__(512, 2) void flash_attn_split(const u16* __restrict__ Qp, const u16* __restrict__ Kp,
                                                           const u16* __restrict__ VTp, u16* __restrict__ P0,
                                                           float* __restrict__ ml0, float* __restrict__ ml1,
                                                           u16* __restrict__ Op) {
  __shared__ u16 Ks[2][64 * 256];
  __shared__ u16 Vs[2][128 * 128];
  int bid = (int)blockIdx.x;
  int b = (bid & 7) >> 1;
  int j = ((bid & 1) << 5) + (bid >> 3);  // 0..63
  int tid = threadIdx.x;
  int w = tid >> 6, l = tid & 63;
  int l31 = l & 31, lh = l >> 5;
  int q_local = w * 32 + l31;
  u16* KsBase = &Ks[0][0];
  u16* VsBase = &Vs[0][0];

  for (int seg = 0; seg < 2; ++seg) {
    int t = seg ? (63 - j) : j;
    int nkv = (t >> 1) + 1;
    int half = (nkv + 1) >> 1;
    int kb = seg ? half : 0;
    int ke = seg ? nkv : half;
    size_t qrow = (size_t)b * 16384 + (size_t)t * 256 + q_local;
    int s_g = t * 32 + (q_local >> 3);
    float* mlbuf = seg ? ml1 : ml0;
    if (kb >= ke) {
      if (lh == 0) { mlbuf[qrow * 2] = -3.0e38f; mlbuf[qrow * 2 + 1] = 0.f; }
      continue;
    }
    bf16x8 qf[16];
    const u16* qp = Qp + qrow * HD_ + lh * 8;
#pragma unroll
    for (int st = 0; st < 16; ++st) qf[st] = *(const bf16x8*)(qp + st * 16);
    f32x16 oacc[8] = {};
    float m_r = -3.0e38f, l_r = 0.f;
    FLASH_SEG_BODY();
    float inv = 1.0f / l_r;
    u16* ob = (seg ? Op : P0) + qrow * 256;
#pragma unroll
    for (int dt = 0; dt < 8; ++dt) {
#pragma unroll
      for (int jj = 0; jj < 4; ++jj) {
        int d0 = dt * 32 + jj * 8 + 4 * lh;
        u16 o4[4];
#pragma unroll
        for (int e = 0; e < 4; ++e) o4[e] = f2bf(oacc[dt][jj * 4 + e] * inv);
        *(ull*)(ob + d0) = *(const ull*)o4;
      }
    }
    if (lh == 0) { mlbuf[qrow * 2] = m_r; mlbuf[qrow * 2 + 1] = l_r; }
  }
}

// ---------------- combine (coalesced): thread = (row, 16B col chunk) ----------------
__global__ __launch_bounds__(256) void combine_parts(const u16* __restrict__ P0, const float* __restrict__ ml0,
                                                     const float* __restrict__ ml1, u16* __restrict__ O) {
  int idx = blockIdx.x * 256 + threadIdx.x;  // 65536 rows * 32 chunks
  int r = idx >> 5;
  int c = (idx & 31) * 8;
  float m0 = ml0[(size_t)r * 2], l0 = ml0[(size_t)r * 2 + 1];
  float m1 = ml1[(size_t)r * 2], l1 = ml1[(size_t)r * 2 + 1];
  float M = fmaxf(m0, m1);
  float w0 = l0 * exp2f(m0 - M), w1 = l1 * exp2f(m1 - M);
  float inv = 1.0f / (w0 + w1);
  w0 *= inv; w1 *= inv;
  uint4 a = *(const uint4*)(P0 + (size_t)r * 256 + c);
  uint4 bq = *(const uint4*)(O + (size_t)r * 256 + c);
  const u16* ua = (const u16*)&a;
  const u16* ub = (const u16*)&bq;
  u16 o[8];
#pragma unroll
  for (int e = 0; e < 8; ++e) o[e] = f2bf(w0 * bf2f(ua[e]) + w1 * bf2f(ub[e]));
  *(uint4*)(O + (size_t)r * 256 + c) = *(const uint4*)o;
}

extern "C" void kernel_launch(void* const* d_in, const int* in_sizes, int n_in,
                              void* d_out, int out_size, void* d_ws, size_t ws_size,
                              hipStream_t stream) {
  const float* x = (const float*)d_in[0];
  const float* w_qkv = (const float*)d_in[1];
  const float* b_qkv = (const float*)d_in[2];
  const float* w_o = (const float*)d_in[3];
  const float* b_o = (const float*)d_in[4];
  const float* freqs = (const float*)d_in[5];
  // d_in[6] is the causal mask; causality is implemented directly.

  char* ws = (char*)d_ws;
  u16* xb    = (u16*)ws;                          // 33,554,432 B
  u16* wqkvT = (u16*)(ws + 33554432);             // 10,485,760 B
  u16* woT   = (u16*)(ws + 44040192);             //  8,388,608 B
  u16* qkv   = (u16*)(ws + 52428800);             // 41,943,040 B
  u16* qall  = (u16*)(ws + 94371840);             // 33,554,432 B
  u16* kbuf  = (u16*)(ws + 127926272);            //  4,194,304 B
  u16* vbuf  = (u16*)(ws + 132120576);            //  4,194,304 B
  u16* part0 = (u16*)(ws + 136314880);            // 33,554,432 B
  float* ml0 = (float*)(ws + 169869312);          //    524,288 B
  float* ml1 = (float*)(ws + 170393600);          //    524,288 B  -> need 170,917,888
  u16* vT    = xb;    // alias: xb dead after QKV GEMM
  u16* attout = qkv;  // alias: qkv dead after rope_scatter

  cast_f32_bf16<<<2048, 256, 0, stream>>>(x, xb, (B_ * S_ * HID_) / 8);
  transpose_cast<<<dim3(QKVN / 32, HID_ / 32), dim3(32, 8), 0, stream>>>(w_qkv, wqkvT, HID_, QKVN);
  transpose_cast<<<dim3(HID_ / 32, HID_ / 32), dim3(32, 8), 0, stream>>>(w_o, woT, HID_, HID_);
  gemm256n128<<<dim3(32 * 20), 512, 0, stream>>>(xb, wqkvT, b_qkv, qkv, B_ * S_, QKVN, HID_);
  rope_scatter<<<2048, 256, 0, stream>>>(qkv, freqs, qall, kbuf, vbuf);
  transpose_bf16<<<dim3(HD_ / 32, S_ / 32, B_), dim3(32, 8), 0, stream>>>(vbuf, vT, S_, HD_);
  flash_attn_split<<<256, 512, 0, stream>>>(qall, kbuf, vT, part0, ml0, ml1, attout);
  combine_parts<<<8192, 256, 0, stream>>>(part0, ml0, ml1, attout);
  gemm256<true><<<dim3(32 * 8), 512, 0, stream>>>(attout, woT, b_o, d_out, B_ * S_, HID_, HID_);
}